// Round 1
// baseline (1995.075 us; speedup 1.0000x reference)
//
#include <hip/hip_runtime.h>

typedef __attribute__((ext_vector_type(8))) short short8;
typedef __attribute__((ext_vector_type(4))) short short4v;
typedef __attribute__((ext_vector_type(4))) float f32x4;

__device__ __forceinline__ unsigned short f2bf(float f) {
  union { float f; unsigned u; } v; v.f = f;
  unsigned r = v.u + 0x7FFFu + ((v.u >> 16) & 1u);
  return (unsigned short)(r >> 16);
}

// ---------------------------------------------------------------------------
// Kernel 1: Wt[n][k] = bf16( [Wk | Wv](k, n) )   (B^T layout, n in [0,1536))
// ---------------------------------------------------------------------------
__global__ __launch_bounds__(256) void prep_w(const float* __restrict__ Wk,
                                              const float* __restrict__ Wv,
                                              unsigned short* __restrict__ Wt) {
  int idx = blockIdx.x * 256 + threadIdx.x;           // 1536*768 elements
  int n = idx / 768, k = idx - n * 768;
  float w = (n < 768) ? Wk[k * 768 + n] : Wv[k * 768 + (n - 768)];
  Wt[idx] = f2bf(w);
}

// ---------------------------------------------------------------------------
// Kernel 2: q = scale * x[:, :10] @ Wq  -> q_ws[b][h][16][64] bf16 (rows 10..15 = 0)
// one block per batch b; 256 threads, 3 output cols each, 10 t-rows in regs
// ---------------------------------------------------------------------------
__global__ __launch_bounds__(256) void q_proj(const float* __restrict__ x,
                                              const float* __restrict__ Wq,
                                              unsigned short* __restrict__ q_ws) {
  int b = blockIdx.x, tid = threadIdx.x;
  __shared__ float xr[7680];                          // x[b, 0:10, :]
  const float* xp = x + (long)b * 4096 * 768;
  for (int i = tid; i < 7680; i += 256) xr[i] = xp[i];
  // zero padded rows t = 10..15 (independent region)
  for (int i = tid; i < 12 * 6 * 64; i += 256) {
    int h = i / 384, rem = i - h * 384;
    int t = 10 + rem / 64, d = rem & 63;
    q_ws[(((long)(b * 12 + h) * 16 + t) << 6) + d] = 0;
  }
  __syncthreads();
  float acc[10][3];
#pragma unroll
  for (int t = 0; t < 10; ++t) { acc[t][0] = 0.f; acc[t][1] = 0.f; acc[t][2] = 0.f; }
  for (int k = 0; k < 768; ++k) {
    const float* wr = Wq + (long)k * 768;
    float w0 = wr[tid], w1 = wr[tid + 256], w2 = wr[tid + 512];
#pragma unroll
    for (int t = 0; t < 10; ++t) {
      float xv = xr[t * 768 + k];
      acc[t][0] += xv * w0; acc[t][1] += xv * w1; acc[t][2] += xv * w2;
    }
  }
#pragma unroll
  for (int t = 0; t < 10; ++t) {
#pragma unroll
    for (int j = 0; j < 3; ++j) {
      int c = tid + j * 256;
      int h = c >> 6, d = c & 63;
      q_ws[(((long)(b * 12 + h) * 16 + t) << 6) + d] = f2bf(acc[t][j] * 0.125f);
    }
  }
}

// ---------------------------------------------------------------------------
// Kernel 3: [262144 x 768] @ [768 x 1536] bf16 MFMA GEMM.
// cols 0..767 -> k_ws (bf16, [B,H,N,d]); cols 768..1535 -> v_out (fp32, [B,H,N,d])
// 128x128 tile, BK=32, 4 waves (2x2), reg-staged A (fp32->bf16), XOR-swizzled LDS.
// ---------------------------------------------------------------------------
__global__ __launch_bounds__(256) void gemm_kv(const float* __restrict__ x,
                                               const unsigned short* __restrict__ Wt,
                                               unsigned short* __restrict__ k_ws,
                                               float* __restrict__ v_out) {
  __shared__ char lds[32768];                         // A: 2x8192 @0, B: 2x8192 @16384
  int bid = blockIdx.x;
  int lb = (bid & 7) * 3072 + (bid >> 3);             // XCD swizzle (24576 % 8 == 0)
  int mt = lb / 12, nt = lb - mt * 12;
  long m0 = (long)mt * 128; int n0 = nt * 128;
  int tid = threadIdx.x, lane = tid & 63;
  int wid = tid >> 6, wm = wid >> 1, wn = wid & 1;
  int rlo = lane & 15, gk = lane >> 4;

  const float* xs = x + m0 * 768;
  const unsigned short* wp = Wt + (long)n0 * 768;

  int arow0 = tid >> 3, ak4 = (tid & 7) << 2;         // A staging: row, k-float4
  int bn = tid >> 1, bg = (tid & 1) << 1;             // B staging: row n, chunk pair

  f32x4 acc[4][4];
#pragma unroll
  for (int i = 0; i < 4; ++i)
#pragma unroll
    for (int j = 0; j < 4; ++j) acc[i][j] = (f32x4){0.f, 0.f, 0.f, 0.f};

  float4 fA[4]; short8 wB[2];
  // ---- prologue: stage tile 0 ----
#pragma unroll
  for (int it = 0; it < 4; ++it) {
    int row = it * 32 + arow0;
    fA[it] = *(const float4*)(xs + (long)row * 768 + ak4);
  }
#pragma unroll
  for (int i = 0; i < 2; ++i)
    wB[i] = *(const short8*)(wp + (long)bn * 768 + (bg + i) * 8);
#pragma unroll
  for (int it = 0; it < 4; ++it) {
    int row = it * 32 + arow0;
    short4v h;
    h[0] = (short)f2bf(fA[it].x); h[1] = (short)f2bf(fA[it].y);
    h[2] = (short)f2bf(fA[it].z); h[3] = (short)f2bf(fA[it].w);
    *(short4v*)(lds + row * 64 + ((ak4 * 2) ^ (((row >> 1) & 3) << 4))) = h;
  }
#pragma unroll
  for (int i = 0; i < 2; ++i)
    *(short8*)(lds + 16384 + bn * 64 + (((bg + i) * 16) ^ (((bn >> 1) & 3) << 4))) = wB[i];
  __syncthreads();

#pragma unroll 2
  for (int ks = 0; ks < 24; ++ks) {
    char* Ab = lds + (ks & 1) * 8192;
    char* Bb = lds + 16384 + (ks & 1) * 8192;
    bool pf = (ks + 1 < 24);
    if (pf) {                                         // issue next-tile loads early
#pragma unroll
      for (int it = 0; it < 4; ++it) {
        int row = it * 32 + arow0;
        fA[it] = *(const float4*)(xs + (long)row * 768 + (ks + 1) * 32 + ak4);
      }
#pragma unroll
      for (int i = 0; i < 2; ++i)
        wB[i] = *(const short8*)(wp + (long)bn * 768 + (ks + 1) * 32 + (bg + i) * 8);
    }
    short8 af[4], bfr[4];
#pragma unroll
    for (int mi = 0; mi < 4; ++mi) {
      int row = wm * 64 + mi * 16 + rlo;
      af[mi] = *(const short8*)(Ab + row * 64 + ((gk * 16) ^ (((row >> 1) & 3) << 4)));
    }
#pragma unroll
    for (int ni = 0; ni < 4; ++ni) {
      int n = wn * 64 + ni * 16 + rlo;
      bfr[ni] = *(const short8*)(Bb + n * 64 + ((gk * 16) ^ (((n >> 1) & 3) << 4)));
    }
#pragma unroll
    for (int mi = 0; mi < 4; ++mi)
#pragma unroll
      for (int ni = 0; ni < 4; ++ni)
        acc[mi][ni] = __builtin_amdgcn_mfma_f32_16x16x32_bf16(af[mi], bfr[ni], acc[mi][ni], 0, 0, 0);
    if (pf) {                                         // write next tile after MFMA
      char* An = lds + ((ks + 1) & 1) * 8192;
      char* Bn = lds + 16384 + ((ks + 1) & 1) * 8192;
#pragma unroll
      for (int it = 0; it < 4; ++it) {
        int row = it * 32 + arow0;
        short4v h;
        h[0] = (short)f2bf(fA[it].x); h[1] = (short)f2bf(fA[it].y);
        h[2] = (short)f2bf(fA[it].z); h[3] = (short)f2bf(fA[it].w);
        *(short4v*)(An + row * 64 + ((ak4 * 2) ^ (((row >> 1) & 3) << 4))) = h;
      }
#pragma unroll
      for (int i = 0; i < 2; ++i)
        *(short8*)(Bn + bn * 64 + (((bg + i) * 16) ^ (((bn >> 1) & 3) << 4))) = wB[i];
    }
    __syncthreads();
  }

  // ---- epilogue: D col = lane&15, row = (lane>>4)*4 + r ----
  bool is_k = (n0 < 768);                             // uniform per block
  int cb = is_k ? n0 : n0 - 768;
#pragma unroll
  for (int ni = 0; ni < 4; ++ni) {
    int cc = cb + wn * 64 + ni * 16 + rlo;
    int h = cc >> 6, d = cc & 63;
#pragma unroll
    for (int mi = 0; mi < 4; ++mi) {
#pragma unroll
      for (int r = 0; r < 4; ++r) {
        long m = m0 + wm * 64 + mi * 16 + gk * 4 + r;
        int b = (int)(m >> 12), n = (int)(m & 4095);
        long off = ((long)(b * 12 + h) * 4096 + n) * 64 + d;
        float val = acc[mi][ni][r];
        if (is_k) k_ws[off] = f2bf(val);
        else      v_out[off] = val;
      }
    }
  }
}

// ---------------------------------------------------------------------------
// Kernel 4: fused attention per (b,h). 512 threads / 8 waves.
// Phase 1: QK^T via mfma(K,Q) -> raw scores (masked) into attn_out + row max
// Phase 2: row sum of exp;  Phase 3: PV (p recomputed in A-frag layout)
// Phase 4: in-place normalize raw scores -> final attn;  preproj write
// ---------------------------------------------------------------------------
__global__ __launch_bounds__(512) void attn_fused(const unsigned short* __restrict__ k_ws,
                                                  const unsigned short* __restrict__ q_ws,
                                                  const float* __restrict__ v_glob,
                                                  float* __restrict__ attn_out,
                                                  float* __restrict__ preproj) {
  __shared__ float red[8][16];
  __shared__ float rowmax[16];
  __shared__ float rowinv[16];
  __shared__ float scratch[8 * 256];

  int tid = threadIdx.x, lane = tid & 63, w = tid >> 6;
  int bh = blockIdx.x;
  int r16 = lane & 15, gk = lane >> 4;
  int trc = (r16 < 10) ? r16 : 9;                     // clamped row for reads

  const unsigned short* kp = k_ws + (long)bh * (4096 * 64);
  const unsigned short* qp = q_ws + (long)bh * 1024;
  float* sraw = attn_out + (long)bh * 40960;          // raw-score staging = attn region
  const float* vp = v_glob + (long)bh * (4096 * 64);

  short8 qf0 = *(const short8*)(qp + r16 * 64 + gk * 8);
  short8 qf1 = *(const short8*)(qp + r16 * 64 + 32 + gk * 8);

  // ---- Phase 1: scores + row max ----
  float pmax = -3.0e38f;
  for (int ch = 0; ch < 32; ++ch) {
    int n0 = (w * 32 + ch) << 4;
    short8 kf0 = *(const short8*)(kp + (long)(n0 + r16) * 64 + gk * 8);
    short8 kf1 = *(const short8*)(kp + (long)(n0 + r16) * 64 + 32 + gk * 8);
    f32x4 d4 = (f32x4){0.f, 0.f, 0.f, 0.f};
    d4 = __builtin_amdgcn_mfma_f32_16x16x32_bf16(kf0, qf0, d4, 0, 0, 0);
    d4 = __builtin_amdgcn_mfma_f32_16x16x32_bf16(kf1, qf1, d4, 0, 0, 0);
    float sv[4];
#pragma unroll
    for (int r = 0; r < 4; ++r) {
      int n = n0 + gk * 4 + r;
      float s = d4[r];
      if (n < 10 && n != r16) s = -1e30f;             // task-token mask
      sv[r] = s;
      pmax = fmaxf(pmax, s);
    }
    if (r16 < 10)
      *(float4*)(sraw + r16 * 4096 + n0 + gk * 4) = make_float4(sv[0], sv[1], sv[2], sv[3]);
  }
  pmax = fmaxf(pmax, __shfl_xor(pmax, 16));
  pmax = fmaxf(pmax, __shfl_xor(pmax, 32));
  if (lane < 16) red[w][lane] = pmax;
  __syncthreads();
  if (tid < 16) {
    float m = red[0][tid];
#pragma unroll
    for (int i = 1; i < 8; ++i) m = fmaxf(m, red[i][tid]);
    rowmax[tid] = m;
  }
  __syncthreads();

  // ---- Phase 2: row sum ----
  float mx = rowmax[trc];
  float psum = 0.f;
  for (int ch = 0; ch < 16; ++ch) {
    int n0 = ((w * 16 + ch) << 5) + gk * 8;
    float4 a = *(const float4*)(sraw + trc * 4096 + n0);
    float4 b2 = *(const float4*)(sraw + trc * 4096 + n0 + 4);
    psum += __expf(a.x - mx) + __expf(a.y - mx) + __expf(a.z - mx) + __expf(a.w - mx)
          + __expf(b2.x - mx) + __expf(b2.y - mx) + __expf(b2.z - mx) + __expf(b2.w - mx);
  }
  psum += __shfl_xor(psum, 16);
  psum += __shfl_xor(psum, 32);
  if (lane < 16) red[w][lane] = psum;
  __syncthreads();
  if (tid < 16) {
    float s = 0.f;
#pragma unroll
    for (int i = 0; i < 8; ++i) s += red[i][tid];
    rowinv[tid] = 1.0f / s;
  }
  __syncthreads();

  // ---- Phase 3: PV. wave w: d-chunk (w&3), n-half (w>>2) ----
  int dc = w & 3, half = w >> 2;
  int d0 = dc << 4;
  float inv = rowinv[trc];
  f32x4 acc = (f32x4){0.f, 0.f, 0.f, 0.f};
  for (int kk = 0; kk < 64; ++kk) {
    int nr = half * 2048 + kk * 32 + gk * 8;
    float4 s0 = *(const float4*)(sraw + trc * 4096 + nr);
    float4 s1 = *(const float4*)(sraw + trc * 4096 + nr + 4);
    short8 pa;
    pa[0] = (short)f2bf(__expf(s0.x - mx) * inv);
    pa[1] = (short)f2bf(__expf(s0.y - mx) * inv);
    pa[2] = (short)f2bf(__expf(s0.z - mx) * inv);
    pa[3] = (short)f2bf(__expf(s0.w - mx) * inv);
    pa[4] = (short)f2bf(__expf(s1.x - mx) * inv);
    pa[5] = (short)f2bf(__expf(s1.y - mx) * inv);
    pa[6] = (short)f2bf(__expf(s1.z - mx) * inv);
    pa[7] = (short)f2bf(__expf(s1.w - mx) * inv);
    short8 vb;
    const float* vrow = vp + (long)nr * 64 + d0 + r16;
#pragma unroll
    for (int j = 0; j < 8; ++j) vb[j] = (short)f2bf(vrow[j * 64]);
    acc = __builtin_amdgcn_mfma_f32_16x16x32_bf16(pa, vb, acc, 0, 0, 0);
  }
#pragma unroll
  for (int r = 0; r < 4; ++r)
    scratch[w * 256 + (gk * 4 + r) * 16 + r16] = acc[r];   // D: row=t, col=d-local
  __syncthreads();

  // ---- preproj write ----
  int b = bh / 12, h = bh - b * 12;
  for (int idx = tid; idx < 640; idx += 512) {
    int tt = idx >> 6, d = idx & 63;
    int c = d >> 4, dl = d & 15;
    float s = scratch[c * 256 + tt * 16 + dl] + scratch[(c + 4) * 256 + tt * 16 + dl];
    preproj[((long)b * 10 + tt) * 768 + h * 64 + d] = s;
  }

  // ---- Phase 4: normalize raw scores in place -> final attn ----
  if (r16 < 10) {
    for (int ch = 0; ch < 16; ++ch) {
      int nn = ((w * 16 + ch) << 5) + gk * 8;
      float* sp = sraw + r16 * 4096 + nn;
      float4 a = *(const float4*)(sp);
      float4 b2 = *(const float4*)(sp + 4);
      a.x = __expf(a.x - mx) * inv;  a.y = __expf(a.y - mx) * inv;
      a.z = __expf(a.z - mx) * inv;  a.w = __expf(a.w - mx) * inv;
      b2.x = __expf(b2.x - mx) * inv; b2.y = __expf(b2.y - mx) * inv;
      b2.z = __expf(b2.z - mx) * inv; b2.w = __expf(b2.w - mx) * inv;
      *(float4*)(sp) = a;
      *(float4*)(sp + 4) = b2;
    }
  }
}

// ---------------------------------------------------------------------------
// Kernel 5: x_cls = preproj @ Wp + bp   (one block per batch b)
// ---------------------------------------------------------------------------
__global__ __launch_bounds__(256) void proj_out_k(const float* __restrict__ preproj,
                                                  const float* __restrict__ Wp,
                                                  const float* __restrict__ bp,
                                                  float* __restrict__ out0) {
  int b = blockIdx.x, tid = threadIdx.x;
  __shared__ float xr[7680];
  const float* pp = preproj + (long)b * 7680;
  for (int i = tid; i < 7680; i += 256) xr[i] = pp[i];
  __syncthreads();
  float acc[10][3];
#pragma unroll
  for (int t = 0; t < 10; ++t) { acc[t][0] = 0.f; acc[t][1] = 0.f; acc[t][2] = 0.f; }
  for (int k = 0; k < 768; ++k) {
    const float* wr = Wp + (long)k * 768;
    float w0 = wr[tid], w1 = wr[tid + 256], w2 = wr[tid + 512];
#pragma unroll
    for (int t = 0; t < 10; ++t) {
      float xv = xr[t * 768 + k];
      acc[t][0] += xv * w0; acc[t][1] += xv * w1; acc[t][2] += xv * w2;
    }
  }
  float b0 = bp[tid], b1 = bp[tid + 256], b2 = bp[tid + 512];
  float* op = out0 + (long)b * 7680;
#pragma unroll
  for (int t = 0; t < 10; ++t) {
    op[t * 768 + tid]       = acc[t][0] + b0;
    op[t * 768 + tid + 256] = acc[t][1] + b1;
    op[t * 768 + tid + 512] = acc[t][2] + b2;
  }
}

// ---------------------------------------------------------------------------
extern "C" void kernel_launch(void* const* d_in, const int* in_sizes, int n_in,
                              void* d_out, int out_size, void* d_ws, size_t ws_size,
                              hipStream_t stream) {
  (void)in_sizes; (void)n_in; (void)out_size; (void)ws_size;
  const float* x  = (const float*)d_in[0];
  const float* Wq = (const float*)d_in[1];
  const float* Wk = (const float*)d_in[2];
  const float* Wv = (const float*)d_in[3];
  const float* Wp = (const float*)d_in[4];
  const float* bp = (const float*)d_in[5];

  float* out      = (float*)d_out;
  float* attn_out = out + 491520;                 // [64,12,10,4096]
  float* v_out    = out + 31948800;               // [64,12,4096,64]

  char* ws = (char*)d_ws;                         // needs ~409 MB
  unsigned short* k_ws = (unsigned short*)(ws);                 // 402,653,184 B
  unsigned short* q_ws = (unsigned short*)(ws + 402653184);     //   1,572,864 B
  unsigned short* Wt   = (unsigned short*)(ws + 404226048);     //   2,359,296 B
  float* preproj       = (float*)(ws + 406585344);              //   1,966,080 B

  prep_w<<<dim3(4608), dim3(256), 0, stream>>>(Wk, Wv, Wt);
  q_proj<<<dim3(64), dim3(256), 0, stream>>>(x, Wq, q_ws);
  gemm_kv<<<dim3(24576), dim3(256), 0, stream>>>(x, Wt, k_ws, v_out);
  attn_fused<<<dim3(768), dim3(512), 0, stream>>>(k_ws, q_ws, v_out, attn_out, preproj);
  proj_out_k<<<dim3(64), dim3(256), 0, stream>>>(preproj, Wp, bp, out);
}

// Round 2
// 1885.290 us; speedup vs baseline: 1.0582x; 1.0582x over previous
//
#include <hip/hip_runtime.h>

typedef __attribute__((ext_vector_type(8))) short short8;
typedef __attribute__((ext_vector_type(4))) short short4v;
typedef __attribute__((ext_vector_type(4))) float f32x4;

__device__ __forceinline__ unsigned short f2bf(float f) {
  union { float f; unsigned u; } v; v.f = f;
  unsigned r = v.u + 0x7FFFu + ((v.u >> 16) & 1u);
  return (unsigned short)(r >> 16);
}

__device__ __forceinline__ void gload16(const void* g, void* l) {
  __builtin_amdgcn_global_load_lds(
      (const __attribute__((address_space(1))) void*)g,
      (__attribute__((address_space(3))) void*)l, 16, 0, 0);
}

// ---------------------------------------------------------------------------
// Kernel 0: x (fp32) -> x_bf16, vectorized 8 elems/thread
// ---------------------------------------------------------------------------
__global__ __launch_bounds__(256) void conv_x(const float* __restrict__ x,
                                              unsigned short* __restrict__ xb) {
  const long total = 25165824;                        // 201326592 / 8
  long stride = (long)gridDim.x * 256;
  for (long u = blockIdx.x * 256 + threadIdx.x; u < total; u += stride) {
    const float* p = x + u * 8;
    float4 a = *(const float4*)p;
    float4 b = *(const float4*)(p + 4);
    short8 h;
    h[0] = (short)f2bf(a.x); h[1] = (short)f2bf(a.y);
    h[2] = (short)f2bf(a.z); h[3] = (short)f2bf(a.w);
    h[4] = (short)f2bf(b.x); h[5] = (short)f2bf(b.y);
    h[6] = (short)f2bf(b.z); h[7] = (short)f2bf(b.w);
    *(short8*)(xb + u * 8) = h;
  }
}

// ---------------------------------------------------------------------------
// Kernel 1: Wt[n][k] = bf16( [Wk | Wv](k, n) )   (B^T layout, n in [0,1536))
// ---------------------------------------------------------------------------
__global__ __launch_bounds__(256) void prep_w(const float* __restrict__ Wk,
                                              const float* __restrict__ Wv,
                                              unsigned short* __restrict__ Wt) {
  int idx = blockIdx.x * 256 + threadIdx.x;           // 1536*768 elements
  int n = idx / 768, k = idx - n * 768;
  float w = (n < 768) ? Wk[k * 768 + n] : Wv[k * 768 + (n - 768)];
  Wt[idx] = f2bf(w);
}

// ---------------------------------------------------------------------------
// Kernel 2: q = scale * x[:, :10] @ Wq  -> q_ws[b][h][16][64] bf16 (rows 10..15 = 0)
// ---------------------------------------------------------------------------
__global__ __launch_bounds__(256) void q_proj(const float* __restrict__ x,
                                              const float* __restrict__ Wq,
                                              unsigned short* __restrict__ q_ws) {
  int b = blockIdx.x, tid = threadIdx.x;
  __shared__ float xr[7680];
  const float* xp = x + (long)b * 4096 * 768;
  for (int i = tid; i < 7680; i += 256) xr[i] = xp[i];
  for (int i = tid; i < 12 * 6 * 64; i += 256) {
    int h = i / 384, rem = i - h * 384;
    int t = 10 + rem / 64, d = rem & 63;
    q_ws[(((long)(b * 12 + h) * 16 + t) << 6) + d] = 0;
  }
  __syncthreads();
  float acc[10][3];
#pragma unroll
  for (int t = 0; t < 10; ++t) { acc[t][0] = 0.f; acc[t][1] = 0.f; acc[t][2] = 0.f; }
  for (int k = 0; k < 768; ++k) {
    const float* wr = Wq + (long)k * 768;
    float w0 = wr[tid], w1 = wr[tid + 256], w2 = wr[tid + 512];
#pragma unroll
    for (int t = 0; t < 10; ++t) {
      float xv = xr[t * 768 + k];
      acc[t][0] += xv * w0; acc[t][1] += xv * w1; acc[t][2] += xv * w2;
    }
  }
#pragma unroll
  for (int t = 0; t < 10; ++t) {
#pragma unroll
    for (int j = 0; j < 3; ++j) {
      int c = tid + j * 256;
      int h = c >> 6, d = c & 63;
      q_ws[(((long)(b * 12 + h) * 16 + t) << 6) + d] = f2bf(acc[t][j] * 0.125f);
    }
  }
}

// ---------------------------------------------------------------------------
// Kernel 3 (NEW, m97 structure): [262144 x 768] @ [768 x 1536] bf16 MFMA GEMM.
// A = x_bf16 via global_load_lds(16B); 128x128 tile, BK=32, single-buffer LDS,
// 2 barriers/K-step. cols 0..767 -> k_ws bf16; cols 768..1535 -> v_out fp32.
// ---------------------------------------------------------------------------
__global__ __launch_bounds__(256) void gemm_kv2(const unsigned short* __restrict__ xb,
                                                const unsigned short* __restrict__ Wt,
                                                unsigned short* __restrict__ k_ws,
                                                float* __restrict__ v_out) {
  __shared__ unsigned short Asm[128 * 32];            // 8 KB, linear [row][k]
  __shared__ unsigned short Bsm[128 * 32];            // 8 KB, linear [n][k]
  int bid = blockIdx.x;
  int lb = (bid & 7) * 3072 + (bid >> 3);             // XCD swizzle (24576 % 8 == 0)
  int mt = lb / 12, nt = lb - mt * 12;
  long m0 = (long)mt * 128; int n0 = nt * 128;
  int tid = threadIdx.x, lane = tid & 63;
  int uw = __builtin_amdgcn_readfirstlane(tid >> 6);  // uniform wave id
  int wm = uw >> 1, wn = uw & 1;
  int r16 = lane & 15, gk = lane >> 4;

  const unsigned short* xs = xb + m0 * 768;
  const unsigned short* wp = Wt + (long)n0 * 768;

  int srow = lane >> 2;                               // row within 16-row chunk
  int scol = (lane & 3) << 3;                         // k-offset (8 bf16 = 16B)

  f32x4 acc[4][4];
#pragma unroll
  for (int i = 0; i < 4; ++i)
#pragma unroll
    for (int j = 0; j < 4; ++j) acc[i][j] = (f32x4){0.f, 0.f, 0.f, 0.f};

  for (int ks = 0; ks < 24; ++ks) {
    if (ks) __syncthreads();                          // prev-iter frag reads done
    int kb = ks * 32;
#pragma unroll
    for (int i = 0; i < 2; ++i) {
      int c = i * 4 + uw;                             // 16-row chunk index 0..7
      gload16(xs + (long)(c * 16 + srow) * 768 + kb + scol, &Asm[c * 512]);
      gload16(wp + (long)(c * 16 + srow) * 768 + kb + scol, &Bsm[c * 512]);
    }
    __syncthreads();                                  // vmcnt(0) drain + barrier
    short8 af[4], bfr[4];
#pragma unroll
    for (int mi = 0; mi < 4; ++mi)
      af[mi] = *(const short8*)&Asm[(wm * 64 + mi * 16 + r16) * 32 + gk * 8];
#pragma unroll
    for (int ni = 0; ni < 4; ++ni)
      bfr[ni] = *(const short8*)&Bsm[(wn * 64 + ni * 16 + r16) * 32 + gk * 8];
#pragma unroll
    for (int mi = 0; mi < 4; ++mi)
#pragma unroll
      for (int ni = 0; ni < 4; ++ni)
        acc[mi][ni] = __builtin_amdgcn_mfma_f32_16x16x32_bf16(af[mi], bfr[ni], acc[mi][ni], 0, 0, 0);
  }

  // ---- epilogue: D col = lane&15, row = (lane>>4)*4 + r ----
  bool is_k = (n0 < 768);
  int cb = is_k ? n0 : n0 - 768;
#pragma unroll
  for (int ni = 0; ni < 4; ++ni) {
    int cc = cb + wn * 64 + ni * 16 + r16;
    int h = cc >> 6, d = cc & 63;
#pragma unroll
    for (int mi = 0; mi < 4; ++mi) {
#pragma unroll
      for (int r = 0; r < 4; ++r) {
        long m = m0 + wm * 64 + mi * 16 + gk * 4 + r;
        int b = (int)(m >> 12), n = (int)(m & 4095);
        long off = ((long)(b * 12 + h) * 4096 + n) * 64 + d;
        float val = acc[mi][ni][r];
        if (is_k) k_ws[off] = f2bf(val);
        else      v_out[off] = val;
      }
    }
  }
}

// ---------------------------------------------------------------------------
// Kernel 3-FALLBACK (R1 version, used when ws_size is too small)
// ---------------------------------------------------------------------------
__global__ __launch_bounds__(256) void gemm_kv(const float* __restrict__ x,
                                               const unsigned short* __restrict__ Wt,
                                               unsigned short* __restrict__ k_ws,
                                               float* __restrict__ v_out) {
  __shared__ char lds[32768];
  int bid = blockIdx.x;
  int lb = (bid & 7) * 3072 + (bid >> 3);
  int mt = lb / 12, nt = lb - mt * 12;
  long m0 = (long)mt * 128; int n0 = nt * 128;
  int tid = threadIdx.x, lane = tid & 63;
  int wid = tid >> 6, wm = wid >> 1, wn = wid & 1;
  int rlo = lane & 15, gk = lane >> 4;

  const float* xs = x + m0 * 768;
  const unsigned short* wp = Wt + (long)n0 * 768;

  int arow0 = tid >> 3, ak4 = (tid & 7) << 2;
  int bn = tid >> 1, bg = (tid & 1) << 1;

  f32x4 acc[4][4];
#pragma unroll
  for (int i = 0; i < 4; ++i)
#pragma unroll
    for (int j = 0; j < 4; ++j) acc[i][j] = (f32x4){0.f, 0.f, 0.f, 0.f};

  float4 fA[4]; short8 wB[2];
#pragma unroll
  for (int it = 0; it < 4; ++it) {
    int row = it * 32 + arow0;
    fA[it] = *(const float4*)(xs + (long)row * 768 + ak4);
  }
#pragma unroll
  for (int i = 0; i < 2; ++i)
    wB[i] = *(const short8*)(wp + (long)bn * 768 + (bg + i) * 8);
#pragma unroll
  for (int it = 0; it < 4; ++it) {
    int row = it * 32 + arow0;
    short4v h;
    h[0] = (short)f2bf(fA[it].x); h[1] = (short)f2bf(fA[it].y);
    h[2] = (short)f2bf(fA[it].z); h[3] = (short)f2bf(fA[it].w);
    *(short4v*)(lds + row * 64 + ((ak4 * 2) ^ (((row >> 1) & 3) << 4))) = h;
  }
#pragma unroll
  for (int i = 0; i < 2; ++i)
    *(short8*)(lds + 16384 + bn * 64 + (((bg + i) * 16) ^ (((bn >> 1) & 3) << 4))) = wB[i];
  __syncthreads();

#pragma unroll 2
  for (int ks = 0; ks < 24; ++ks) {
    char* Ab = lds + (ks & 1) * 8192;
    char* Bb = lds + 16384 + (ks & 1) * 8192;
    bool pf = (ks + 1 < 24);
    if (pf) {
#pragma unroll
      for (int it = 0; it < 4; ++it) {
        int row = it * 32 + arow0;
        fA[it] = *(const float4*)(xs + (long)row * 768 + (ks + 1) * 32 + ak4);
      }
#pragma unroll
      for (int i = 0; i < 2; ++i)
        wB[i] = *(const short8*)(wp + (long)bn * 768 + (ks + 1) * 32 + (bg + i) * 8);
    }
    short8 af[4], bfr[4];
#pragma unroll
    for (int mi = 0; mi < 4; ++mi) {
      int row = wm * 64 + mi * 16 + rlo;
      af[mi] = *(const short8*)(Ab + row * 64 + ((gk * 16) ^ (((row >> 1) & 3) << 4)));
    }
#pragma unroll
    for (int ni = 0; ni < 4; ++ni) {
      int n = wn * 64 + ni * 16 + rlo;
      bfr[ni] = *(const short8*)(Bb + n * 64 + ((gk * 16) ^ (((n >> 1) & 3) << 4)));
    }
#pragma unroll
    for (int mi = 0; mi < 4; ++mi)
#pragma unroll
      for (int ni = 0; ni < 4; ++ni)
        acc[mi][ni] = __builtin_amdgcn_mfma_f32_16x16x32_bf16(af[mi], bfr[ni], acc[mi][ni], 0, 0, 0);
    if (pf) {
      char* An = lds + ((ks + 1) & 1) * 8192;
      char* Bn = lds + 16384 + ((ks + 1) & 1) * 8192;
#pragma unroll
      for (int it = 0; it < 4; ++it) {
        int row = it * 32 + arow0;
        short4v h;
        h[0] = (short)f2bf(fA[it].x); h[1] = (short)f2bf(fA[it].y);
        h[2] = (short)f2bf(fA[it].z); h[3] = (short)f2bf(fA[it].w);
        *(short4v*)(An + row * 64 + ((ak4 * 2) ^ (((row >> 1) & 3) << 4))) = h;
      }
#pragma unroll
      for (int i = 0; i < 2; ++i)
        *(short8*)(Bn + bn * 64 + (((bg + i) * 16) ^ (((bn >> 1) & 3) << 4))) = wB[i];
    }
    __syncthreads();
  }

  bool is_k = (n0 < 768);
  int cb = is_k ? n0 : n0 - 768;
#pragma unroll
  for (int ni = 0; ni < 4; ++ni) {
    int cc = cb + wn * 64 + ni * 16 + rlo;
    int h = cc >> 6, d = cc & 63;
#pragma unroll
    for (int mi = 0; mi < 4; ++mi) {
#pragma unroll
      for (int r = 0; r < 4; ++r) {
        long m = m0 + wm * 64 + mi * 16 + gk * 4 + r;
        int b = (int)(m >> 12), n = (int)(m & 4095);
        long off = ((long)(b * 12 + h) * 4096 + n) * 64 + d;
        float val = acc[mi][ni][r];
        if (is_k) k_ws[off] = f2bf(val);
        else      v_out[off] = val;
      }
    }
  }
}

// ---------------------------------------------------------------------------
// Kernel 4: fused attention per (b,h). 512 threads / 8 waves.
// ---------------------------------------------------------------------------
__global__ __launch_bounds__(512) void attn_fused(const unsigned short* __restrict__ k_ws,
                                                  const unsigned short* __restrict__ q_ws,
                                                  const float* __restrict__ v_glob,
                                                  float* __restrict__ attn_out,
                                                  float* __restrict__ preproj) {
  __shared__ float red[8][16];
  __shared__ float rowmax[16];
  __shared__ float rowinv[16];
  __shared__ float scratch[8 * 256];

  int tid = threadIdx.x, lane = tid & 63, w = tid >> 6;
  int bh = blockIdx.x;
  int r16 = lane & 15, gk = lane >> 4;
  int trc = (r16 < 10) ? r16 : 9;

  const unsigned short* kp = k_ws + (long)bh * (4096 * 64);
  const unsigned short* qp = q_ws + (long)bh * 1024;
  float* sraw = attn_out + (long)bh * 40960;
  const float* vp = v_glob + (long)bh * (4096 * 64);

  short8 qf0 = *(const short8*)(qp + r16 * 64 + gk * 8);
  short8 qf1 = *(const short8*)(qp + r16 * 64 + 32 + gk * 8);

  // ---- Phase 1: scores + row max ----
  float pmax = -3.0e38f;
  for (int ch = 0; ch < 32; ++ch) {
    int n0 = (w * 32 + ch) << 4;
    short8 kf0 = *(const short8*)(kp + (long)(n0 + r16) * 64 + gk * 8);
    short8 kf1 = *(const short8*)(kp + (long)(n0 + r16) * 64 + 32 + gk * 8);
    f32x4 d4 = (f32x4){0.f, 0.f, 0.f, 0.f};
    d4 = __builtin_amdgcn_mfma_f32_16x16x32_bf16(kf0, qf0, d4, 0, 0, 0);
    d4 = __builtin_amdgcn_mfma_f32_16x16x32_bf16(kf1, qf1, d4, 0, 0, 0);
    float sv[4];
#pragma unroll
    for (int r = 0; r < 4; ++r) {
      int n = n0 + gk * 4 + r;
      float s = d4[r];
      if (n < 10 && n != r16) s = -1e30f;
      sv[r] = s;
      pmax = fmaxf(pmax, s);
    }
    if (r16 < 10)
      *(float4*)(sraw + r16 * 4096 + n0 + gk * 4) = make_float4(sv[0], sv[1], sv[2], sv[3]);
  }
  pmax = fmaxf(pmax, __shfl_xor(pmax, 16));
  pmax = fmaxf(pmax, __shfl_xor(pmax, 32));
  if (lane < 16) red[w][lane] = pmax;
  __syncthreads();
  if (tid < 16) {
    float m = red[0][tid];
#pragma unroll
    for (int i = 1; i < 8; ++i) m = fmaxf(m, red[i][tid]);
    rowmax[tid] = m;
  }
  __syncthreads();

  // ---- Phase 2: row sum ----
  float mx = rowmax[trc];
  float psum = 0.f;
  for (int ch = 0; ch < 16; ++ch) {
    int n0 = ((w * 16 + ch) << 5) + gk * 8;
    float4 a = *(const float4*)(sraw + trc * 4096 + n0);
    float4 b2 = *(const float4*)(sraw + trc * 4096 + n0 + 4);
    psum += __expf(a.x - mx) + __expf(a.y - mx) + __expf(a.z - mx) + __expf(a.w - mx)
          + __expf(b2.x - mx) + __expf(b2.y - mx) + __expf(b2.z - mx) + __expf(b2.w - mx);
  }
  psum += __shfl_xor(psum, 16);
  psum += __shfl_xor(psum, 32);
  if (lane < 16) red[w][lane] = psum;
  __syncthreads();
  if (tid < 16) {
    float s = 0.f;
#pragma unroll
    for (int i = 0; i < 8; ++i) s += red[i][tid];
    rowinv[tid] = 1.0f / s;
  }
  __syncthreads();

  // ---- Phase 3: PV ----
  int dc = w & 3, half = w >> 2;
  int d0 = dc << 4;
  float inv = rowinv[trc];
  f32x4 acc = (f32x4){0.f, 0.f, 0.f, 0.f};
  for (int kk = 0; kk < 64; ++kk) {
    int nr = half * 2048 + kk * 32 + gk * 8;
    float4 s0 = *(const float4*)(sraw + trc * 4096 + nr);
    float4 s1 = *(const float4*)(sraw + trc * 4096 + nr + 4);
    short8 pa;
    pa[0] = (short)f2bf(__expf(s0.x - mx) * inv);
    pa[1] = (short)f2bf(__expf(s0.y - mx) * inv);
    pa[2] = (short)f2bf(__expf(s0.z - mx) * inv);
    pa[3] = (short)f2bf(__expf(s0.w - mx) * inv);
    pa[4] = (short)f2bf(__expf(s1.x - mx) * inv);
    pa[5] = (short)f2bf(__expf(s1.y - mx) * inv);
    pa[6] = (short)f2bf(__expf(s1.z - mx) * inv);
    pa[7] = (short)f2bf(__expf(s1.w - mx) * inv);
    short8 vb;
    const float* vrow = vp + (long)nr * 64 + d0 + r16;
#pragma unroll
    for (int j = 0; j < 8; ++j) vb[j] = (short)f2bf(vrow[j * 64]);
    acc = __builtin_amdgcn_mfma_f32_16x16x32_bf16(pa, vb, acc, 0, 0, 0);
  }
#pragma unroll
  for (int r = 0; r < 4; ++r)
    scratch[w * 256 + (gk * 4 + r) * 16 + r16] = acc[r];
  __syncthreads();

  int b = bh / 12, h = bh - b * 12;
  for (int idx = tid; idx < 640; idx += 512) {
    int tt = idx >> 6, d = idx & 63;
    int c = d >> 4, dl = d & 15;
    float s = scratch[c * 256 + tt * 16 + dl] + scratch[(c + 4) * 256 + tt * 16 + dl];
    preproj[((long)b * 10 + tt) * 768 + h * 64 + d] = s;
  }

  // ---- Phase 4: normalize raw scores in place ----
  if (r16 < 10) {
    for (int ch = 0; ch < 16; ++ch) {
      int nn = ((w * 16 + ch) << 5) + gk * 8;
      float* sp = sraw + r16 * 4096 + nn;
      float4 a = *(const float4*)(sp);
      float4 b2 = *(const float4*)(sp + 4);
      a.x = __expf(a.x - mx) * inv;  a.y = __expf(a.y - mx) * inv;
      a.z = __expf(a.z - mx) * inv;  a.w = __expf(a.w - mx) * inv;
      b2.x = __expf(b2.x - mx) * inv; b2.y = __expf(b2.y - mx) * inv;
      b2.z = __expf(b2.z - mx) * inv; b2.w = __expf(b2.w - mx) * inv;
      *(float4*)(sp) = a;
      *(float4*)(sp + 4) = b2;
    }
  }
}

// ---------------------------------------------------------------------------
// Kernel 5: x_cls = preproj @ Wp + bp
// ---------------------------------------------------------------------------
__global__ __launch_bounds__(256) void proj_out_k(const float* __restrict__ preproj,
                                                  const float* __restrict__ Wp,
                                                  const float* __restrict__ bp,
                                                  float* __restrict__ out0) {
  int b = blockIdx.x, tid = threadIdx.x;
  __shared__ float xr[7680];
  const float* pp = preproj + (long)b * 7680;
  for (int i = tid; i < 7680; i += 256) xr[i] = pp[i];
  __syncthreads();
  float acc[10][3];
#pragma unroll
  for (int t = 0; t < 10; ++t) { acc[t][0] = 0.f; acc[t][1] = 0.f; acc[t][2] = 0.f; }
  for (int k = 0; k < 768; ++k) {
    const float* wr = Wp + (long)k * 768;
    float w0 = wr[tid], w1 = wr[tid + 256], w2 = wr[tid + 512];
#pragma unroll
    for (int t = 0; t < 10; ++t) {
      float xv = xr[t * 768 + k];
      acc[t][0] += xv * w0; acc[t][1] += xv * w1; acc[t][2] += xv * w2;
    }
  }
  float b0 = bp[tid], b1 = bp[tid + 256], b2 = bp[tid + 512];
  float* op = out0 + (long)b * 7680;
#pragma unroll
  for (int t = 0; t < 10; ++t) {
    op[t * 768 + tid]       = acc[t][0] + b0;
    op[t * 768 + tid + 256] = acc[t][1] + b1;
    op[t * 768 + tid + 512] = acc[t][2] + b2;
  }
}

// ---------------------------------------------------------------------------
extern "C" void kernel_launch(void* const* d_in, const int* in_sizes, int n_in,
                              void* d_out, int out_size, void* d_ws, size_t ws_size,
                              hipStream_t stream) {
  (void)in_sizes; (void)n_in; (void)out_size;
  const float* x  = (const float*)d_in[0];
  const float* Wq = (const float*)d_in[1];
  const float* Wk = (const float*)d_in[2];
  const float* Wv = (const float*)d_in[3];
  const float* Wp = (const float*)d_in[4];
  const float* bp = (const float*)d_in[5];

  float* out      = (float*)d_out;
  float* attn_out = out + 491520;                 // [64,12,10,4096]
  float* v_out    = out + 31948800;               // [64,12,4096,64]

  char* ws = (char*)d_ws;
  const size_t NEED_BIG = 811204608;              // x_bf16 + k_ws + small

  if (ws_size >= NEED_BIG) {
    unsigned short* x_bf16 = (unsigned short*)(ws);               // 402,653,184 B
    unsigned short* k_ws = (unsigned short*)(ws + 402653184);     // 402,653,184 B
    unsigned short* q_ws = (unsigned short*)(ws + 805306368);     //   1,572,864 B
    unsigned short* Wt   = (unsigned short*)(ws + 806879232);     //   2,359,296 B
    float* preproj       = (float*)(ws + 809238528);              //   1,966,080 B

    conv_x<<<dim3(2048), dim3(256), 0, stream>>>(x, x_bf16);
    prep_w<<<dim3(4608), dim3(256), 0, stream>>>(Wk, Wv, Wt);
    q_proj<<<dim3(64), dim3(256), 0, stream>>>(x, Wq, q_ws);
    gemm_kv2<<<dim3(24576), dim3(256), 0, stream>>>(x_bf16, Wt, k_ws, v_out);
    attn_fused<<<dim3(768), dim3(512), 0, stream>>>(k_ws, q_ws, v_out, attn_out, preproj);
    proj_out_k<<<dim3(64), dim3(256), 0, stream>>>(preproj, Wp, bp, out);
  } else {
    unsigned short* k_ws = (unsigned short*)(ws);                 // 402,653,184 B
    unsigned short* q_ws = (unsigned short*)(ws + 402653184);
    unsigned short* Wt   = (unsigned short*)(ws + 404226048);
    float* preproj       = (float*)(ws + 406585344);

    prep_w<<<dim3(4608), dim3(256), 0, stream>>>(Wk, Wv, Wt);
    q_proj<<<dim3(64), dim3(256), 0, stream>>>(x, Wq, q_ws);
    gemm_kv<<<dim3(24576), dim3(256), 0, stream>>>(x, Wt, k_ws, v_out);
    attn_fused<<<dim3(768), dim3(512), 0, stream>>>(k_ws, q_ws, v_out, attn_out, preproj);
    proj_out_k<<<dim3(64), dim3(256), 0, stream>>>(preproj, Wp, bp, out);
  }
}